// Round 11
// baseline (31.974 us; speedup 1.0000x reference)
//
#include <hip/hip_runtime.h>

#define BATCH 8192
#define NG 3
#define NE 32
#define D 128
#define NPAIR (BATCH * NG)            // 24576
#define TILE 32                       // tokens per MFMA sub-tile
#define CHUNK 2048                    // pairs scanned per block
#define NCHUNK (NPAIR / CHUNK)        // 12
#define NFIN (BATCH * 16 / 256)       // 512 final blocks

typedef __attribute__((ext_vector_type(8))) short short8;
typedef __attribute__((ext_vector_type(4))) float f32x4;

// ---------------- workspace layout (bytes) ----------------
#define OFF_YB   0                                      // bf16 [NPAIR][D], 6 MB
#define OFF_YB2  ((size_t)NPAIR * D * 2)                // bf16 [NPAIR][D], 6 MB
#define WS_REQUIRED (OFF_YB2 + (size_t)NPAIR * D * 2)   // ~12.6 MB

static __device__ __forceinline__ ushort f2bf(float f) {
    unsigned b = __float_as_uint(f);
    unsigned r = (b + 0x7FFFu + ((b >> 16) & 1u)) >> 16;   // RNE
    return (ushort)r;
}
static __device__ __forceinline__ float bf2f(ushort u) {
    return __uint_as_float(((unsigned)u) << 16);
}
static __device__ __forceinline__ unsigned pk2(float lo, float hi) {
    return (unsigned)f2bf(lo) | ((unsigned)f2bf(hi) << 16);
}

// ================= self-dispatching grouped GEMM, column-split =================
// Block (chunk, hcol, e). Software-pipelined prologue:
//   phase 0: issue 32 W f32 loads to regs (no deps)      <- L2 latency ...
//   phase 1: int4 scan of 2048-pair slice -> ushort list <- ... hidden here
//   phase 2: pack W -> bf16, XOR-swizzled LDS write
//   phase 3: 32-token sub-tiles: stage x, 8 MFMA/wave, write by pair id.
// LDS: 16K (sW) + 8K (sX) + 4K (list) = 28.7K -> 4 blocks/CU, 16 waves/CU.
template<int LAYER>
static __device__ __forceinline__ void gemm_body(
    const float* __restrict__ x, const ushort* __restrict__ ybin,
    const int* __restrict__ genres, const float* __restrict__ W,
    ushort* __restrict__ ydst)
{
    const int bx = blockIdx.x;
    const int chunk = bx >> 1, hcol = bx & 1;
    const int e = blockIdx.y + 1;          // experts 1..31 (0 = padding)
    const int pbase = chunk * CHUNK;

    __shared__ ushort sW[64 * D];          // swizzled [col_local][k], 16 KB
    __shared__ ushort sX[TILE * D];        // 8 KB
    __shared__ ushort list[CHUNK];         // 4 KB (pair ids < 65536)
    __shared__ int scnt;

    const int tid = threadIdx.x;

    // phase 0: issue W half loads early; latency overlaps the scan below.
    // thread covers col c = tid-ish, 4 consecutive k per iter; coalesced.
    const float* Ws = W + (size_t)e * D * D + hcol * 64;
    float wv[32];
    #pragma unroll
    for (int i = 0; i < 8; ++i) {
        int idx = i * 256 + tid;           // 0..2047
        int c = idx & 63;                  // local col
        int k4 = idx >> 6;                 // 0..31 -> k = 4*k4
        wv[i * 4 + 0] = Ws[(size_t)(4 * k4 + 0) * D + c];
        wv[i * 4 + 1] = Ws[(size_t)(4 * k4 + 1) * D + c];
        wv[i * 4 + 2] = Ws[(size_t)(4 * k4 + 2) * D + c];
        wv[i * 4 + 3] = Ws[(size_t)(4 * k4 + 3) * D + c];
    }

    if (tid == 0) scnt = 0;
    __syncthreads();

    // phase 1: build match list via int4 scan (order scheduling-dependent;
    // output invariant: each pair's value depends only on (token, expert)
    // and is written by pair id)
    const int4* g4 = (const int4*)(genres + pbase);
    #pragma unroll
    for (int i = 0; i < CHUNK / 1024; ++i) {
        int4 gv = g4[i * 256 + tid];
        int p = pbase + (i * 256 + tid) * 4;
        if (gv.x == e) list[atomicAdd(&scnt, 1)] = (ushort)(p + 0);
        if (gv.y == e) list[atomicAdd(&scnt, 1)] = (ushort)(p + 1);
        if (gv.z == e) list[atomicAdd(&scnt, 1)] = (ushort)(p + 2);
        if (gv.w == e) list[atomicAdd(&scnt, 1)] = (ushort)(p + 3);
    }
    __syncthreads();
    const int ntotal = scnt;
    if (ntotal == 0) return;

    // phase 2: pack prefetched W -> sW[c][k] bf16, XOR-swizzled rows
    char* sWb = (char*)sW;
    #pragma unroll
    for (int i = 0; i < 8; ++i) {
        int idx = i * 256 + tid;
        int c = idx & 63;
        int k4 = idx >> 6;
        int byteoff = (c * 256 + k4 * 8) ^ ((c & 7) << 4);
        uint2 q = { pk2(wv[i * 4 + 0], wv[i * 4 + 1]),
                    pk2(wv[i * 4 + 2], wv[i * 4 + 3]) };
        *(uint2*)(sWb + byteoff) = q;
    }
    // sW-write/read barrier provided by the loop's leading __syncthreads()

    const int wave = tid >> 6, lane = tid & 63;
    const int g = lane >> 4, l15 = lane & 15;
    const int colb = wave * 16;            // local col base of this wave
    char* sXb = (char*)sX;

    for (int t0 = 0; t0 < ntotal; t0 += TILE) {
        const int nt = min(TILE, ntotal - t0);
        __syncthreads();                   // sW ready / sX safe to overwrite

        // stage x: 8 threads per token, 16 cols each (full K=128 needed)
        {
            const int t = tid >> 3, th = tid & 7;
            int p = list[t0 + ((t < nt) ? t : 0)];
            int row = p / NG;
            int g0 = genres[row * NG + 0];
            int g1 = genres[row * NG + 1];
            int g2 = genres[row * NG + 2];
            int cnt = (g0 != 0) + (g1 != 0) + (g2 != 0);
            float scale = 1.0f / (float)((cnt > 0) ? cnt : 1);
            unsigned q[8];
            if (LAYER == 1) {
                const float* xp = x + (size_t)row * D + th * 16;
                float v[16];
                *(float4*)&v[0]  = *(const float4*)(xp);
                *(float4*)&v[4]  = *(const float4*)(xp + 4);
                *(float4*)&v[8]  = *(const float4*)(xp + 8);
                *(float4*)&v[12] = *(const float4*)(xp + 12);
                #pragma unroll
                for (int j = 0; j < 8; ++j)
                    q[j] = pk2(v[2*j] * scale, v[2*j+1] * scale);
            } else {
                float s[16];
                #pragma unroll
                for (int j = 0; j < 16; ++j) s[j] = 0.0f;
                #pragma unroll
                for (int slot = 0; slot < NG; ++slot) {
                    int gg = (slot == 0) ? g0 : (slot == 1) ? g1 : g2;
                    if (gg != 0) {
                        const ushort* yp = ybin + ((size_t)row * NG + slot) * D + th * 16;
                        uint4 va = *(const uint4*)yp;
                        uint4 vb = *(const uint4*)(yp + 8);
                        unsigned w[8] = { va.x, va.y, va.z, va.w,
                                          vb.x, vb.y, vb.z, vb.w };
                        #pragma unroll
                        for (int j = 0; j < 8; ++j) {
                            s[2*j]   += bf2f((ushort)(w[j] & 0xFFFF));
                            s[2*j+1] += bf2f((ushort)(w[j] >> 16));
                        }
                    }
                }
                #pragma unroll
                for (int j = 0; j < 8; ++j) {
                    float lo = s[2*j],  hi = s[2*j+1];
                    lo = ((lo >= 0.f) ? lo : 0.01f * lo) * scale;
                    hi = ((hi >= 0.f) ? hi : 0.01f * hi) * scale;
                    q[j] = pk2(lo, hi);
                }
            }
            int b0 = (t * 256 + (th * 2) * 16)     ^ ((t & 7) << 4);
            int b1 = (t * 256 + (th * 2 + 1) * 16) ^ ((t & 7) << 4);
            *(uint4*)(sXb + b0) = make_uint4(q[0], q[1], q[2], q[3]);
            *(uint4*)(sXb + b1) = make_uint4(q[4], q[5], q[6], q[7]);
        }
        __syncthreads();

        f32x4 acc0 = {0.f,0.f,0.f,0.f}, acc1 = {0.f,0.f,0.f,0.f};

        #pragma unroll
        for (int ks = 0; ks < 4; ++ks) {
            const int kb = ks * 64 + g * 16;
            int c0 = colb + l15;           // local col 0..63
            short8 a0 = *(const short8*)(sWb + ((c0 * 256 + kb) ^ ((c0 & 7) << 4)));
            int t0l = l15, t1l = l15 + 16;
            short8 b0 = *(const short8*)(sXb + ((t0l * 256 + kb) ^ ((t0l & 7) << 4)));
            short8 b1 = *(const short8*)(sXb + ((t1l * 256 + kb) ^ ((t1l & 7) << 4)));
            acc0 = __builtin_amdgcn_mfma_f32_16x16x32_bf16(a0, b0, acc0, 0, 0, 0);
            acc1 = __builtin_amdgcn_mfma_f32_16x16x32_bf16(a0, b1, acc1, 0, 0, 0);
        }

        #pragma unroll
        for (int n = 0; n < 2; ++n) {
            int tok = n * 16 + l15;
            if (tok < nt) {
                int p = list[t0 + tok];
                ushort* dst = ydst + (size_t)p * D + hcol * 64 + colb + g * 4;
                f32x4 v = (n == 0) ? acc0 : acc1;
                ushort4 pq = { f2bf(v[0]), f2bf(v[1]), f2bf(v[2]), f2bf(v[3]) };
                *(ushort4*)dst = pq;
            }
        }
    }
}

__global__ __launch_bounds__(256, 4) void moe_gemm1_kernel(
    const float* __restrict__ x, const int* __restrict__ genres,
    const float* __restrict__ W0, ushort* __restrict__ yb)
{
    gemm_body<1>(x, nullptr, genres, W0, yb);
}

__global__ __launch_bounds__(256, 4) void moe_gemm2_kernel(
    const ushort* __restrict__ yb, const int* __restrict__ genres,
    const float* __restrict__ W1, ushort* __restrict__ yb2)
{
    gemm_body<2>(nullptr, yb, genres, W1, yb2);
}

// ---------------- final: out[b] = lrelu(sum_live yb2[b,slot]) f32 ----------------
__global__ __launch_bounds__(256) void moe_final_kernel(
    const ushort* __restrict__ yb2, const int* __restrict__ genres,
    float* __restrict__ out)
{
    int gid = blockIdx.x * 256 + threadIdx.x;   // BATCH*16 chunks of 8
    int b = gid >> 4, c8 = (gid & 15) * 8;
    int g0 = genres[b * NG + 0];
    int g1 = genres[b * NG + 1];
    int g2 = genres[b * NG + 2];

    float s[8] = {0,0,0,0,0,0,0,0};
    #pragma unroll
    for (int slot = 0; slot < NG; ++slot) {
        int g = (slot == 0) ? g0 : (slot == 1) ? g1 : g2;
        if (g != 0) {
            uint4 v = *(const uint4*)&yb2[((size_t)b * NG + slot) * D + c8];
            const unsigned w[4] = { v.x, v.y, v.z, v.w };
            #pragma unroll
            for (int j = 0; j < 4; ++j) {
                s[2*j]   += bf2f((ushort)(w[j] & 0xFFFF));
                s[2*j+1] += bf2f((ushort)(w[j] >> 16));
            }
        }
    }
    float r[8];
    #pragma unroll
    for (int j = 0; j < 8; ++j)
        r[j] = (s[j] >= 0.f) ? s[j] : 0.01f * s[j];
    float4 lo = { r[0], r[1], r[2], r[3] };
    float4 hi = { r[4], r[5], r[6], r[7] };
    *(float4*)&out[(size_t)b * D + c8]     = lo;
    *(float4*)&out[(size_t)b * D + c8 + 4] = hi;
}

// ---------------- round-0 per-token fallback if ws too small ----------------
__global__ __launch_bounds__(128) void moe_layer_kernel(
    const float* __restrict__ x, const int* __restrict__ genres,
    const float* __restrict__ W, float* __restrict__ out)
{
    const int b = blockIdx.x;
    const int o = threadIdx.x;
    __shared__ float xs[D];
    xs[o] = x[(size_t)b * D + o];
    __syncthreads();
    int e0 = genres[b * NG + 0], e1 = genres[b * NG + 1], e2 = genres[b * NG + 2];
    float acc = 0.0f; int cnt = 0;
    #pragma unroll
    for (int g = 0; g < NG; ++g) {
        int e = (g == 0) ? e0 : (g == 1) ? e1 : e2;
        if (e != 0) {
            ++cnt;
            const float* We = W + (size_t)e * D * D + o;
            float a = 0.0f;
            #pragma unroll 8
            for (int i = 0; i < D; ++i) a = fmaf(xs[i], We[(size_t)i * D], a);
            acc += a;
        }
    }
    float r = (cnt > 0) ? (acc / (float)cnt) : 0.0f;
    out[(size_t)b * D + o] = (r >= 0.0f) ? r : 0.01f * r;
}

extern "C" void kernel_launch(void* const* d_in, const int* in_sizes, int n_in,
                              void* d_out, int out_size, void* d_ws, size_t ws_size,
                              hipStream_t stream)
{
    const float* x      = (const float*)d_in[0];
    const int*   genres = (const int*)d_in[1];
    const float* W0     = (const float*)d_in[2];
    const float* W1     = (const float*)d_in[3];
    float*       out    = (float*)d_out;

    if (ws_size < WS_REQUIRED) {
        moe_layer_kernel<<<BATCH, D, 0, stream>>>(x,   genres, W0, out);
        moe_layer_kernel<<<BATCH, D, 0, stream>>>(out, genres, W1, out);
        return;
    }

    char* ws = (char*)d_ws;
    ushort* yb  = (ushort*)(ws + OFF_YB);
    ushort* yb2 = (ushort*)(ws + OFF_YB2);

    dim3 ggrid(NCHUNK * 2, NE - 1);   // (12 chunks x 2 col-halves) x 31 experts
    moe_gemm1_kernel<<<ggrid, 256, 0, stream>>>(x, genres, W0, yb);
    moe_gemm2_kernel<<<ggrid, 256, 0, stream>>>(yb, genres, W1, yb2);
    moe_final_kernel<<<NFIN, 256, 0, stream>>>(yb2, genres, out);
}

// Round 12
// 30.778 us; speedup vs baseline: 1.0389x; 1.0389x over previous
//
#include <hip/hip_runtime.h>

#define BATCH 8192
#define NG 3
#define NE 32
#define D 128
#define NPAIR (BATCH * NG)            // 24576
#define TILE 32                       // tokens per MFMA sub-tile
#define CHUNK 2048                    // pairs scanned per block
#define NCHUNK (NPAIR / CHUNK)        // 12
#define NFIN (BATCH * 16 / 256)       // 512 final blocks

typedef __attribute__((ext_vector_type(8))) short short8;
typedef __attribute__((ext_vector_type(4))) float f32x4;

// ---------------- workspace layout (bytes) ----------------
#define OFF_YB   0                                      // bf16 [NPAIR][D], 6 MB
#define OFF_YB2  ((size_t)NPAIR * D * 2)                // bf16 [NPAIR][D], 6 MB
#define WS_REQUIRED (OFF_YB2 + (size_t)NPAIR * D * 2)   // ~12.6 MB

static __device__ __forceinline__ ushort f2bf(float f) {
    unsigned b = __float_as_uint(f);
    unsigned r = (b + 0x7FFFu + ((b >> 16) & 1u)) >> 16;   // RNE
    return (ushort)r;
}
static __device__ __forceinline__ float bf2f(ushort u) {
    return __uint_as_float(((unsigned)u) << 16);
}
static __device__ __forceinline__ unsigned pk2(float lo, float hi) {
    return (unsigned)f2bf(lo) | ((unsigned)f2bf(hi) << 16);
}

// ================= self-dispatching grouped GEMM, column-split =================
// Block (chunk, hcol, e):
//   phase 1: ATOMIC-FREE wave-ballot compaction of the 2048-pair slice
//            (wave w owns 512 pairs; 8 ballots -> per-wave count -> LDS scan
//             of 4 counts -> ordered scatter at base + popc(mask & lt)).
//   phase 2: stage HALF of W[e] (f32 -> bf16, transpose, XOR-swizzle; 16 KB)
//   phase 3: 32-token sub-tiles: stage x (LAYER 1: f32 * 1/cnt; LAYER 2:
//            fused lrelu(sum yb slots)/cnt), 8 MFMA/wave, write by pair id.
// LDS: 16K (sW) + 8K (sX) + 4K (list) = 28.7K -> 4 blocks/CU, 16 waves/CU.
template<int LAYER>
static __device__ __forceinline__ void gemm_body(
    const float* __restrict__ x, const ushort* __restrict__ ybin,
    const int* __restrict__ genres, const float* __restrict__ W,
    ushort* __restrict__ ydst)
{
    const int bx = blockIdx.x;
    const int chunk = bx >> 1, hcol = bx & 1;
    const int e = blockIdx.y + 1;          // experts 1..31 (0 = padding)
    const int pbase = chunk * CHUNK;

    __shared__ ushort sW[64 * D];          // swizzled [col_local][k], 16 KB
    __shared__ ushort sX[TILE * D];        // 8 KB
    __shared__ ushort list[CHUNK];         // 4 KB (pair ids < 65536)
    __shared__ int wcnt[4];

    const int tid = threadIdx.x;
    const int wv_ = tid >> 6, lane = tid & 63;

    // ---- phase 1: ballot compaction (no atomics) ----
    const int4* g4 = (const int4*)(genres + pbase);
    const unsigned long long lt = (1ull << lane) - 1ull;
    int4 ga = g4[wv_ * 128 + lane];        // pairs pbase + 4*(wv*128+lane) ..
    int4 gb = g4[wv_ * 128 + 64 + lane];
    unsigned long long m0 = __ballot(ga.x == e);
    unsigned long long m1 = __ballot(ga.y == e);
    unsigned long long m2 = __ballot(ga.z == e);
    unsigned long long m3 = __ballot(ga.w == e);
    unsigned long long m4 = __ballot(gb.x == e);
    unsigned long long m5 = __ballot(gb.y == e);
    unsigned long long m6 = __ballot(gb.z == e);
    unsigned long long m7 = __ballot(gb.w == e);
    if (lane == 0)
        wcnt[wv_] = __popcll(m0) + __popcll(m1) + __popcll(m2) + __popcll(m3)
                  + __popcll(m4) + __popcll(m5) + __popcll(m6) + __popcll(m7);
    __syncthreads();

    const int c0_ = wcnt[0], c1_ = wcnt[1], c2_ = wcnt[2], c3_ = wcnt[3];
    const int ntotal = c0_ + c1_ + c2_ + c3_;
    if (ntotal == 0) return;
    int run = (wv_ > 0 ? c0_ : 0) + (wv_ > 1 ? c1_ : 0) + (wv_ > 2 ? c2_ : 0);

    {   // ordered scatter of this wave's matches
        int pa = pbase + (wv_ * 128 + lane) * 4;
        int pb = pa + 256;
        if (ga.x == e) list[run + __popcll(m0 & lt)] = (ushort)(pa + 0);
        run += __popcll(m0);
        if (ga.y == e) list[run + __popcll(m1 & lt)] = (ushort)(pa + 1);
        run += __popcll(m1);
        if (ga.z == e) list[run + __popcll(m2 & lt)] = (ushort)(pa + 2);
        run += __popcll(m2);
        if (ga.w == e) list[run + __popcll(m3 & lt)] = (ushort)(pa + 3);
        run += __popcll(m3);
        if (gb.x == e) list[run + __popcll(m4 & lt)] = (ushort)(pb + 0);
        run += __popcll(m4);
        if (gb.y == e) list[run + __popcll(m5 & lt)] = (ushort)(pb + 1);
        run += __popcll(m5);
        if (gb.z == e) list[run + __popcll(m6 & lt)] = (ushort)(pb + 2);
        run += __popcll(m6);
        if (gb.w == e) list[run + __popcll(m7 & lt)] = (ushort)(pb + 3);
    }

    // ---- phase 2: stage W half: sW[c][k] = bf16(W[k][64*hcol+c]), swizzled
    const float* Ws = W + (size_t)e * D * D + hcol * 64;
    char* sWb = (char*)sW;
    #pragma unroll
    for (int i = 0; i < 8; ++i) {
        int idx = i * 256 + tid;           // 0..2047
        int c = idx & 63;                  // local col
        int k4 = idx >> 6;                 // 0..31 -> k = 4*k4
        float a0 = Ws[(size_t)(4 * k4 + 0) * D + c];
        float a1 = Ws[(size_t)(4 * k4 + 1) * D + c];
        float a2 = Ws[(size_t)(4 * k4 + 2) * D + c];
        float a3 = Ws[(size_t)(4 * k4 + 3) * D + c];
        int byteoff = (c * 256 + k4 * 8) ^ ((c & 7) << 4);
        uint2 q = { pk2(a0, a1), pk2(a2, a3) };
        *(uint2*)(sWb + byteoff) = q;
    }
    // sW/list write -> read barrier provided by the loop's leading __syncthreads()

    const int g = lane >> 4, l15 = lane & 15;
    const int colb = wv_ * 16;             // local col base of this wave
    char* sXb = (char*)sX;

    for (int t0 = 0; t0 < ntotal; t0 += TILE) {
        const int nt = min(TILE, ntotal - t0);
        __syncthreads();                   // sW/list ready / sX safe

        // stage x: 8 threads per token, 16 cols each (full K=128 needed)
        {
            const int t = tid >> 3, th = tid & 7;
            int p = list[t0 + ((t < nt) ? t : 0)];
            int row = p / NG;
            int g0 = genres[row * NG + 0];
            int g1 = genres[row * NG + 1];
            int g2 = genres[row * NG + 2];
            int cnt = (g0 != 0) + (g1 != 0) + (g2 != 0);
            float scale = 1.0f / (float)((cnt > 0) ? cnt : 1);
            unsigned q[8];
            if (LAYER == 1) {
                const float* xp = x + (size_t)row * D + th * 16;
                float v[16];
                *(float4*)&v[0]  = *(const float4*)(xp);
                *(float4*)&v[4]  = *(const float4*)(xp + 4);
                *(float4*)&v[8]  = *(const float4*)(xp + 8);
                *(float4*)&v[12] = *(const float4*)(xp + 12);
                #pragma unroll
                for (int j = 0; j < 8; ++j)
                    q[j] = pk2(v[2*j] * scale, v[2*j+1] * scale);
            } else {
                float s[16];
                #pragma unroll
                for (int j = 0; j < 16; ++j) s[j] = 0.0f;
                #pragma unroll
                for (int slot = 0; slot < NG; ++slot) {
                    int gg = (slot == 0) ? g0 : (slot == 1) ? g1 : g2;
                    if (gg != 0) {
                        const ushort* yp = ybin + ((size_t)row * NG + slot) * D + th * 16;
                        uint4 va = *(const uint4*)yp;
                        uint4 vb = *(const uint4*)(yp + 8);
                        unsigned w[8] = { va.x, va.y, va.z, va.w,
                                          vb.x, vb.y, vb.z, vb.w };
                        #pragma unroll
                        for (int j = 0; j < 8; ++j) {
                            s[2*j]   += bf2f((ushort)(w[j] & 0xFFFF));
                            s[2*j+1] += bf2f((ushort)(w[j] >> 16));
                        }
                    }
                }
                #pragma unroll
                for (int j = 0; j < 8; ++j) {
                    float lo = s[2*j],  hi = s[2*j+1];
                    lo = ((lo >= 0.f) ? lo : 0.01f * lo) * scale;
                    hi = ((hi >= 0.f) ? hi : 0.01f * hi) * scale;
                    q[j] = pk2(lo, hi);
                }
            }
            int b0 = (t * 256 + (th * 2) * 16)     ^ ((t & 7) << 4);
            int b1 = (t * 256 + (th * 2 + 1) * 16) ^ ((t & 7) << 4);
            *(uint4*)(sXb + b0) = make_uint4(q[0], q[1], q[2], q[3]);
            *(uint4*)(sXb + b1) = make_uint4(q[4], q[5], q[6], q[7]);
        }
        __syncthreads();

        f32x4 acc0 = {0.f,0.f,0.f,0.f}, acc1 = {0.f,0.f,0.f,0.f};

        #pragma unroll
        for (int ks = 0; ks < 4; ++ks) {
            const int kb = ks * 64 + g * 16;
            int c0 = colb + l15;           // local col 0..63
            short8 a0 = *(const short8*)(sWb + ((c0 * 256 + kb) ^ ((c0 & 7) << 4)));
            int t0l = l15, t1l = l15 + 16;
            short8 b0 = *(const short8*)(sXb + ((t0l * 256 + kb) ^ ((t0l & 7) << 4)));
            short8 b1 = *(const short8*)(sXb + ((t1l * 256 + kb) ^ ((t1l & 7) << 4)));
            acc0 = __builtin_amdgcn_mfma_f32_16x16x32_bf16(a0, b0, acc0, 0, 0, 0);
            acc1 = __builtin_amdgcn_mfma_f32_16x16x32_bf16(a0, b1, acc1, 0, 0, 0);
        }

        #pragma unroll
        for (int n = 0; n < 2; ++n) {
            int tok = n * 16 + l15;
            if (tok < nt) {
                int p = list[t0 + tok];
                ushort* dst = ydst + (size_t)p * D + hcol * 64 + colb + g * 4;
                f32x4 v = (n == 0) ? acc0 : acc1;
                ushort4 pq = { f2bf(v[0]), f2bf(v[1]), f2bf(v[2]), f2bf(v[3]) };
                *(ushort4*)dst = pq;
            }
        }
    }
}

__global__ __launch_bounds__(256, 4) void moe_gemm1_kernel(
    const float* __restrict__ x, const int* __restrict__ genres,
    const float* __restrict__ W0, ushort* __restrict__ yb)
{
    gemm_body<1>(x, nullptr, genres, W0, yb);
}

__global__ __launch_bounds__(256, 4) void moe_gemm2_kernel(
    const ushort* __restrict__ yb, const int* __restrict__ genres,
    const float* __restrict__ W1, ushort* __restrict__ yb2)
{
    gemm_body<2>(nullptr, yb, genres, W1, yb2);
}

// ---------------- final: out[b] = lrelu(sum_live yb2[b,slot]) f32 ----------------
__global__ __launch_bounds__(256) void moe_final_kernel(
    const ushort* __restrict__ yb2, const int* __restrict__ genres,
    float* __restrict__ out)
{
    int gid = blockIdx.x * 256 + threadIdx.x;   // BATCH*16 chunks of 8
    int b = gid >> 4, c8 = (gid & 15) * 8;
    int g0 = genres[b * NG + 0];
    int g1 = genres[b * NG + 1];
    int g2 = genres[b * NG + 2];

    float s[8] = {0,0,0,0,0,0,0,0};
    #pragma unroll
    for (int slot = 0; slot < NG; ++slot) {
        int g = (slot == 0) ? g0 : (slot == 1) ? g1 : g2;
        if (g != 0) {
            uint4 v = *(const uint4*)&yb2[((size_t)b * NG + slot) * D + c8];
            const unsigned w[4] = { v.x, v.y, v.z, v.w };
            #pragma unroll
            for (int j = 0; j < 4; ++j) {
                s[2*j]   += bf2f((ushort)(w[j] & 0xFFFF));
                s[2*j+1] += bf2f((ushort)(w[j] >> 16));
            }
        }
    }
    float r[8];
    #pragma unroll
    for (int j = 0; j < 8; ++j)
        r[j] = (s[j] >= 0.f) ? s[j] : 0.01f * s[j];
    float4 lo = { r[0], r[1], r[2], r[3] };
    float4 hi = { r[4], r[5], r[6], r[7] };
    *(float4*)&out[(size_t)b * D + c8]     = lo;
    *(float4*)&out[(size_t)b * D + c8 + 4] = hi;
}

// ---------------- round-0 per-token fallback if ws too small ----------------
__global__ __launch_bounds__(128) void moe_layer_kernel(
    const float* __restrict__ x, const int* __restrict__ genres,
    const float* __restrict__ W, float* __restrict__ out)
{
    const int b = blockIdx.x;
    const int o = threadIdx.x;
    __shared__ float xs[D];
    xs[o] = x[(size_t)b * D + o];
    __syncthreads();
    int e0 = genres[b * NG + 0], e1 = genres[b * NG + 1], e2 = genres[b * NG + 2];
    float acc = 0.0f; int cnt = 0;
    #pragma unroll
    for (int g = 0; g < NG; ++g) {
        int e = (g == 0) ? e0 : (g == 1) ? e1 : e2;
        if (e != 0) {
            ++cnt;
            const float* We = W + (size_t)e * D * D + o;
            float a = 0.0f;
            #pragma unroll 8
            for (int i = 0; i < D; ++i) a = fmaf(xs[i], We[(size_t)i * D], a);
            acc += a;
        }
    }
    float r = (cnt > 0) ? (acc / (float)cnt) : 0.0f;
    out[(size_t)b * D + o] = (r >= 0.0f) ? r : 0.01f * r;
}

extern "C" void kernel_launch(void* const* d_in, const int* in_sizes, int n_in,
                              void* d_out, int out_size, void* d_ws, size_t ws_size,
                              hipStream_t stream)
{
    const float* x      = (const float*)d_in[0];
    const int*   genres = (const int*)d_in[1];
    const float* W0     = (const float*)d_in[2];
    const float* W1     = (const float*)d_in[3];
    float*       out    = (float*)d_out;

    if (ws_size < WS_REQUIRED) {
        moe_layer_kernel<<<BATCH, D, 0, stream>>>(x,   genres, W0, out);
        moe_layer_kernel<<<BATCH, D, 0, stream>>>(out, genres, W1, out);
        return;
    }

    char* ws = (char*)d_ws;
    ushort* yb  = (ushort*)(ws + OFF_YB);
    ushort* yb2 = (ushort*)(ws + OFF_YB2);

    dim3 ggrid(NCHUNK * 2, NE - 1);   // (12 chunks x 2 col-halves) x 31 experts
    moe_gemm1_kernel<<<ggrid, 256, 0, stream>>>(x, genres, W0, yb);
    moe_gemm2_kernel<<<ggrid, 256, 0, stream>>>(yb, genres, W1, yb2);
    moe_final_kernel<<<NFIN, 256, 0, stream>>>(yb2, genres, out);
}

// Round 13
// 30.141 us; speedup vs baseline: 1.0608x; 1.0211x over previous
//
#include <hip/hip_runtime.h>

#define BATCH 8192
#define NG 3
#define NE 32
#define D 128
#define NPAIR (BATCH * NG)            // 24576
#define TILE 32                       // tokens per MFMA sub-tile
#define CHUNK 2048                    // pairs scanned per block
#define NCHUNK (NPAIR / CHUNK)        // 12
#define NFIN (BATCH * 16 / 256)       // 512 final blocks

typedef __attribute__((ext_vector_type(8))) short short8;
typedef __attribute__((ext_vector_type(4))) float f32x4;

// ---------------- workspace layout (bytes) ----------------
#define OFF_YB   0                                      // bf16 [NPAIR][D], 6 MB
#define OFF_YB2  ((size_t)NPAIR * D * 2)                // bf16 [NPAIR][D], 6 MB
#define WS_REQUIRED (OFF_YB2 + (size_t)NPAIR * D * 2)   // ~12.6 MB

static __device__ __forceinline__ ushort f2bf(float f) {
    unsigned b = __float_as_uint(f);
    unsigned r = (b + 0x7FFFu + ((b >> 16) & 1u)) >> 16;   // RNE
    return (ushort)r;
}
static __device__ __forceinline__ float bf2f(ushort u) {
    return __uint_as_float(((unsigned)u) << 16);
}
static __device__ __forceinline__ unsigned pk2(float lo, float hi) {
    return (unsigned)f2bf(lo) | ((unsigned)f2bf(hi) << 16);
}

// ================= self-dispatching grouped GEMM, column-split =================
// Block (chunk, hcol, e):
//   phase 1: atomic-free wave-ballot compaction of the 2048-pair slice
//   phase 2: stage HALF of W[e] (f32 -> bf16, transpose, XOR-swizzle; 16 KB)
//   phase 3: 32-token sub-tiles: stage x (LAYER 1: f32 * 1/cnt; LAYER 2:
//            fused lrelu(sum yb slots)/cnt), 8 MFMA/wave, write by pair id.
// LDS: 16K (sW) + 8K (sX) + 4K (list) = 28.7K -> 5 blocks/CU (143.5 KB),
// 20 waves/CU = 5 waves/SIMD for latency hiding. launch_bounds(256,5)
// caps VGPR at ~102 (no spill at current pressure).
template<int LAYER>
static __device__ __forceinline__ void gemm_body(
    const float* __restrict__ x, const ushort* __restrict__ ybin,
    const int* __restrict__ genres, const float* __restrict__ W,
    ushort* __restrict__ ydst)
{
    const int bx = blockIdx.x;
    const int chunk = bx >> 1, hcol = bx & 1;
    const int e = blockIdx.y + 1;          // experts 1..31 (0 = padding)
    const int pbase = chunk * CHUNK;

    __shared__ ushort sW[64 * D];          // swizzled [col_local][k], 16 KB
    __shared__ ushort sX[TILE * D];        // 8 KB
    __shared__ ushort list[CHUNK];         // 4 KB (pair ids < 65536)
    __shared__ int wcnt[4];

    const int tid = threadIdx.x;
    const int wv_ = tid >> 6, lane = tid & 63;

    // ---- phase 1: ballot compaction (no atomics) ----
    const int4* g4 = (const int4*)(genres + pbase);
    const unsigned long long lt = (1ull << lane) - 1ull;
    int4 ga = g4[wv_ * 128 + lane];        // pairs pbase + 4*(wv*128+lane) ..
    int4 gb = g4[wv_ * 128 + 64 + lane];
    unsigned long long m0 = __ballot(ga.x == e);
    unsigned long long m1 = __ballot(ga.y == e);
    unsigned long long m2 = __ballot(ga.z == e);
    unsigned long long m3 = __ballot(ga.w == e);
    unsigned long long m4 = __ballot(gb.x == e);
    unsigned long long m5 = __ballot(gb.y == e);
    unsigned long long m6 = __ballot(gb.z == e);
    unsigned long long m7 = __ballot(gb.w == e);
    if (lane == 0)
        wcnt[wv_] = __popcll(m0) + __popcll(m1) + __popcll(m2) + __popcll(m3)
                  + __popcll(m4) + __popcll(m5) + __popcll(m6) + __popcll(m7);
    __syncthreads();

    const int c0_ = wcnt[0], c1_ = wcnt[1], c2_ = wcnt[2], c3_ = wcnt[3];
    const int ntotal = c0_ + c1_ + c2_ + c3_;
    if (ntotal == 0) return;
    int run = (wv_ > 0 ? c0_ : 0) + (wv_ > 1 ? c1_ : 0) + (wv_ > 2 ? c2_ : 0);

    {   // ordered scatter of this wave's matches
        int pa = pbase + (wv_ * 128 + lane) * 4;
        int pb = pa + 256;
        if (ga.x == e) list[run + __popcll(m0 & lt)] = (ushort)(pa + 0);
        run += __popcll(m0);
        if (ga.y == e) list[run + __popcll(m1 & lt)] = (ushort)(pa + 1);
        run += __popcll(m1);
        if (ga.z == e) list[run + __popcll(m2 & lt)] = (ushort)(pa + 2);
        run += __popcll(m2);
        if (ga.w == e) list[run + __popcll(m3 & lt)] = (ushort)(pa + 3);
        run += __popcll(m3);
        if (gb.x == e) list[run + __popcll(m4 & lt)] = (ushort)(pb + 0);
        run += __popcll(m4);
        if (gb.y == e) list[run + __popcll(m5 & lt)] = (ushort)(pb + 1);
        run += __popcll(m5);
        if (gb.z == e) list[run + __popcll(m6 & lt)] = (ushort)(pb + 2);
        run += __popcll(m6);
        if (gb.w == e) list[run + __popcll(m7 & lt)] = (ushort)(pb + 3);
    }

    // ---- phase 2: stage W half: sW[c][k] = bf16(W[k][64*hcol+c]), swizzled
    const float* Ws = W + (size_t)e * D * D + hcol * 64;
    char* sWb = (char*)sW;
    #pragma unroll
    for (int i = 0; i < 8; ++i) {
        int idx = i * 256 + tid;           // 0..2047
        int c = idx & 63;                  // local col
        int k4 = idx >> 6;                 // 0..31 -> k = 4*k4
        float a0 = Ws[(size_t)(4 * k4 + 0) * D + c];
        float a1 = Ws[(size_t)(4 * k4 + 1) * D + c];
        float a2 = Ws[(size_t)(4 * k4 + 2) * D + c];
        float a3 = Ws[(size_t)(4 * k4 + 3) * D + c];
        int byteoff = (c * 256 + k4 * 8) ^ ((c & 7) << 4);
        uint2 q = { pk2(a0, a1), pk2(a2, a3) };
        *(uint2*)(sWb + byteoff) = q;
    }
    // sW/list write -> read barrier provided by the loop's leading __syncthreads()

    const int g = lane >> 4, l15 = lane & 15;
    const int colb = wv_ * 16;             // local col base of this wave
    char* sXb = (char*)sX;

    for (int t0 = 0; t0 < ntotal; t0 += TILE) {
        const int nt = min(TILE, ntotal - t0);
        __syncthreads();                   // sW/list ready / sX safe

        // stage x: 8 threads per token, 16 cols each (full K=128 needed)
        {
            const int t = tid >> 3, th = tid & 7;
            int p = list[t0 + ((t < nt) ? t : 0)];
            int row = p / NG;
            int g0 = genres[row * NG + 0];
            int g1 = genres[row * NG + 1];
            int g2 = genres[row * NG + 2];
            int cnt = (g0 != 0) + (g1 != 0) + (g2 != 0);
            float scale = 1.0f / (float)((cnt > 0) ? cnt : 1);
            unsigned q[8];
            if (LAYER == 1) {
                const float* xp = x + (size_t)row * D + th * 16;
                float v[16];
                *(float4*)&v[0]  = *(const float4*)(xp);
                *(float4*)&v[4]  = *(const float4*)(xp + 4);
                *(float4*)&v[8]  = *(const float4*)(xp + 8);
                *(float4*)&v[12] = *(const float4*)(xp + 12);
                #pragma unroll
                for (int j = 0; j < 8; ++j)
                    q[j] = pk2(v[2*j] * scale, v[2*j+1] * scale);
            } else {
                float s[16];
                #pragma unroll
                for (int j = 0; j < 16; ++j) s[j] = 0.0f;
                #pragma unroll
                for (int slot = 0; slot < NG; ++slot) {
                    int gg = (slot == 0) ? g0 : (slot == 1) ? g1 : g2;
                    if (gg != 0) {
                        const ushort* yp = ybin + ((size_t)row * NG + slot) * D + th * 16;
                        uint4 va = *(const uint4*)yp;
                        uint4 vb = *(const uint4*)(yp + 8);
                        unsigned w[8] = { va.x, va.y, va.z, va.w,
                                          vb.x, vb.y, vb.z, vb.w };
                        #pragma unroll
                        for (int j = 0; j < 8; ++j) {
                            s[2*j]   += bf2f((ushort)(w[j] & 0xFFFF));
                            s[2*j+1] += bf2f((ushort)(w[j] >> 16));
                        }
                    }
                }
                #pragma unroll
                for (int j = 0; j < 8; ++j) {
                    float lo = s[2*j],  hi = s[2*j+1];
                    lo = ((lo >= 0.f) ? lo : 0.01f * lo) * scale;
                    hi = ((hi >= 0.f) ? hi : 0.01f * hi) * scale;
                    q[j] = pk2(lo, hi);
                }
            }
            int b0 = (t * 256 + (th * 2) * 16)     ^ ((t & 7) << 4);
            int b1 = (t * 256 + (th * 2 + 1) * 16) ^ ((t & 7) << 4);
            *(uint4*)(sXb + b0) = make_uint4(q[0], q[1], q[2], q[3]);
            *(uint4*)(sXb + b1) = make_uint4(q[4], q[5], q[6], q[7]);
        }
        __syncthreads();

        f32x4 acc0 = {0.f,0.f,0.f,0.f}, acc1 = {0.f,0.f,0.f,0.f};

        #pragma unroll
        for (int ks = 0; ks < 4; ++ks) {
            const int kb = ks * 64 + g * 16;
            int c0 = colb + l15;           // local col 0..63
            short8 a0 = *(const short8*)(sWb + ((c0 * 256 + kb) ^ ((c0 & 7) << 4)));
            int t0l = l15, t1l = l15 + 16;
            short8 b0 = *(const short8*)(sXb + ((t0l * 256 + kb) ^ ((t0l & 7) << 4)));
            short8 b1 = *(const short8*)(sXb + ((t1l * 256 + kb) ^ ((t1l & 7) << 4)));
            acc0 = __builtin_amdgcn_mfma_f32_16x16x32_bf16(a0, b0, acc0, 0, 0, 0);
            acc1 = __builtin_amdgcn_mfma_f32_16x16x32_bf16(a0, b1, acc1, 0, 0, 0);
        }

        #pragma unroll
        for (int n = 0; n < 2; ++n) {
            int tok = n * 16 + l15;
            if (tok < nt) {
                int p = list[t0 + tok];
                ushort* dst = ydst + (size_t)p * D + hcol * 64 + colb + g * 4;
                f32x4 v = (n == 0) ? acc0 : acc1;
                ushort4 pq = { f2bf(v[0]), f2bf(v[1]), f2bf(v[2]), f2bf(v[3]) };
                *(ushort4*)dst = pq;
            }
        }
    }
}

__global__ __launch_bounds__(256, 5) void moe_gemm1_kernel(
    const float* __restrict__ x, const int* __restrict__ genres,
    const float* __restrict__ W0, ushort* __restrict__ yb)
{
    gemm_body<1>(x, nullptr, genres, W0, yb);
}

__global__ __launch_bounds__(256, 5) void moe_gemm2_kernel(
    const ushort* __restrict__ yb, const int* __restrict__ genres,
    const float* __restrict__ W1, ushort* __restrict__ yb2)
{
    gemm_body<2>(nullptr, yb, genres, W1, yb2);
}

// ---------------- final: out[b] = lrelu(sum_live yb2[b,slot]) f32 ----------------
__global__ __launch_bounds__(256) void moe_final_kernel(
    const ushort* __restrict__ yb2, const int* __restrict__ genres,
    float* __restrict__ out)
{
    int gid = blockIdx.x * 256 + threadIdx.x;   // BATCH*16 chunks of 8
    int b = gid >> 4, c8 = (gid & 15) * 8;
    int g0 = genres[b * NG + 0];
    int g1 = genres[b * NG + 1];
    int g2 = genres[b * NG + 2];

    float s[8] = {0,0,0,0,0,0,0,0};
    #pragma unroll
    for (int slot = 0; slot < NG; ++slot) {
        int g = (slot == 0) ? g0 : (slot == 1) ? g1 : g2;
        if (g != 0) {
            uint4 v = *(const uint4*)&yb2[((size_t)b * NG + slot) * D + c8];
            const unsigned w[4] = { v.x, v.y, v.z, v.w };
            #pragma unroll
            for (int j = 0; j < 4; ++j) {
                s[2*j]   += bf2f((ushort)(w[j] & 0xFFFF));
                s[2*j+1] += bf2f((ushort)(w[j] >> 16));
            }
        }
    }
    float r[8];
    #pragma unroll
    for (int j = 0; j < 8; ++j)
        r[j] = (s[j] >= 0.f) ? s[j] : 0.01f * s[j];
    float4 lo = { r[0], r[1], r[2], r[3] };
    float4 hi = { r[4], r[5], r[6], r[7] };
    *(float4*)&out[(size_t)b * D + c8]     = lo;
    *(float4*)&out[(size_t)b * D + c8 + 4] = hi;
}

// ---------------- round-0 per-token fallback if ws too small ----------------
__global__ __launch_bounds__(128) void moe_layer_kernel(
    const float* __restrict__ x, const int* __restrict__ genres,
    const float* __restrict__ W, float* __restrict__ out)
{
    const int b = blockIdx.x;
    const int o = threadIdx.x;
    __shared__ float xs[D];
    xs[o] = x[(size_t)b * D + o];
    __syncthreads();
    int e0 = genres[b * NG + 0], e1 = genres[b * NG + 1], e2 = genres[b * NG + 2];
    float acc = 0.0f; int cnt = 0;
    #pragma unroll
    for (int g = 0; g < NG; ++g) {
        int e = (g == 0) ? e0 : (g == 1) ? e1 : e2;
        if (e != 0) {
            ++cnt;
            const float* We = W + (size_t)e * D * D + o;
            float a = 0.0f;
            #pragma unroll 8
            for (int i = 0; i < D; ++i) a = fmaf(xs[i], We[(size_t)i * D], a);
            acc += a;
        }
    }
    float r = (cnt > 0) ? (acc / (float)cnt) : 0.0f;
    out[(size_t)b * D + o] = (r >= 0.0f) ? r : 0.01f * r;
}

extern "C" void kernel_launch(void* const* d_in, const int* in_sizes, int n_in,
                              void* d_out, int out_size, void* d_ws, size_t ws_size,
                              hipStream_t stream)
{
    const float* x      = (const float*)d_in[0];
    const int*   genres = (const int*)d_in[1];
    const float* W0     = (const float*)d_in[2];
    const float* W1     = (const float*)d_in[3];
    float*       out    = (float*)d_out;

    if (ws_size < WS_REQUIRED) {
        moe_layer_kernel<<<BATCH, D, 0, stream>>>(x,   genres, W0, out);
        moe_layer_kernel<<<BATCH, D, 0, stream>>>(out, genres, W1, out);
        return;
    }

    char* ws = (char*)d_ws;
    ushort* yb  = (ushort*)(ws + OFF_YB);
    ushort* yb2 = (ushort*)(ws + OFF_YB2);

    dim3 ggrid(NCHUNK * 2, NE - 1);   // (12 chunks x 2 col-halves) x 31 experts
    moe_gemm1_kernel<<<ggrid, 256, 0, stream>>>(x, genres, W0, yb);
    moe_gemm2_kernel<<<ggrid, 256, 0, stream>>>(yb, genres, W1, yb2);
    moe_final_kernel<<<NFIN, 256, 0, stream>>>(yb2, genres, out);
}